// Round 2
// baseline (1071.947 us; speedup 1.0000x reference)
//
#include <hip/hip_runtime.h>

#define N 512
#define EPS 1e-4f
#define RL 128            // matrix rows resident in LDS (rows 0..127; always < n since n>=256)
#define KR 48             // rows per wave in registers: r = RL + k*8 + tr, k in [0,48)

// ---- f16 pack/unpack helpers ----
union U32H { uint u; _Float16 h[2]; };
__device__ inline float h_lo(uint x){ U32H t; t.u = x; return (float)t.h[0]; }
__device__ inline float h_hi(uint x){ U32H t; t.u = x; return (float)t.h[1]; }
__device__ inline uint  h_pk(float a, float b){ U32H t; t.h[0] = (_Float16)a; t.h[1] = (_Float16)b; return t.u; }

typedef _Float16 half2v __attribute__((ext_vector_type(2)));
#if __has_builtin(__builtin_amdgcn_fdot2)
__device__ inline float dot2(uint m, uint v, float c){
    return __builtin_amdgcn_fdot2(__builtin_bit_cast(half2v, m), __builtin_bit_cast(half2v, v), c, false);
}
#else
__device__ inline float dot2(uint m, uint v, float c){
    return c + h_lo(m)*h_lo(v) + h_hi(m)*h_hi(v);
}
#endif

// LDS layout (dynamic):
//   uint  mlds[RL*256]   131072 B   rows 0..127, 256 packed col-pairs each
//   float uu[512]          2048 B   row coefficients u (init: ones mask)
//   float vf[512]          2048 B   col coefficients v (fp32, for epilogue)
//   uint  vpk[256]         1024 B   v packed f16x2 (for fdot2)
//   float red[512*9]      18432 B   reduction scratch (stride 9 = bank pad)
#define LDS_BYTES (131072 + 2048 + 2048 + 1024 + 18432)

__global__ __launch_bounds__(512, 2)
void k_sink(const float* __restrict__ A, const int* __restrict__ nrows,
            float* __restrict__ out) {
    extern __shared__ uint lds[];
    uint*  mlds = lds;
    float* uu   = (float*)(lds + RL * 256);
    float* vf   = uu + 512;
    uint*  vpk  = (uint*)(vf + 512);
    float* red  = (float*)(vpk + 256);

    const int b  = blockIdx.x;
    const int n  = nrows[b];
    const int t  = threadIdx.x;
    const int tr = t >> 6;          // wave id 0..7
    const int tc = t & 63;          // lane
    const int c0 = tc * 8;          // this thread's 8 columns [c0, c0+8)
    const size_t base = (size_t)b * (N * N);

    // ---------------- load + convert (A+eps -> f16, zero outside n x n block) ----------------
    uint mreg[KR][4];
#pragma unroll
    for (int k = 0; k < KR; ++k) {
        int r = RL + k * 8 + tr;
        const float4* p = (const float4*)(A + base + (size_t)r * N + c0);
        float4 a0 = p[0], a1 = p[1];
        bool rok = r < n;
        float e0 = (rok && c0 + 0 < n) ? a0.x + EPS : 0.f;
        float e1 = (rok && c0 + 1 < n) ? a0.y + EPS : 0.f;
        float e2 = (rok && c0 + 2 < n) ? a0.z + EPS : 0.f;
        float e3 = (rok && c0 + 3 < n) ? a0.w + EPS : 0.f;
        float e4 = (rok && c0 + 4 < n) ? a1.x + EPS : 0.f;
        float e5 = (rok && c0 + 5 < n) ? a1.y + EPS : 0.f;
        float e6 = (rok && c0 + 6 < n) ? a1.z + EPS : 0.f;
        float e7 = (rok && c0 + 7 < n) ? a1.w + EPS : 0.f;
        mreg[k][0] = h_pk(e0, e1); mreg[k][1] = h_pk(e2, e3);
        mreg[k][2] = h_pk(e4, e5); mreg[k][3] = h_pk(e6, e7);
    }
#pragma unroll
    for (int k = 0; k < 16; ++k) {
        int r = k * 8 + tr;         // r < 128 <= n always
        const float4* p = (const float4*)(A + base + (size_t)r * N + c0);
        float4 a0 = p[0], a1 = p[1];
        uint4 q;
        q.x = h_pk((c0 + 0 < n) ? a0.x + EPS : 0.f, (c0 + 1 < n) ? a0.y + EPS : 0.f);
        q.y = h_pk((c0 + 2 < n) ? a0.z + EPS : 0.f, (c0 + 3 < n) ? a0.w + EPS : 0.f);
        q.z = h_pk((c0 + 4 < n) ? a1.x + EPS : 0.f, (c0 + 5 < n) ? a1.y + EPS : 0.f);
        q.w = h_pk((c0 + 6 < n) ? a1.z + EPS : 0.f, (c0 + 7 < n) ? a1.w + EPS : 0.f);
        *(uint4*)(mlds + (size_t)r * 256 + tc * 4) = q;
    }
    uu[t] = (t < n) ? 1.f : 0.f;    // iteration-0 column weights
    __syncthreads();

    // ---------------- 10 Sinkhorn steps = 5 x (col, row) ----------------
    for (int it = 0; it < 5; ++it) {
        // --- col step: vf[c] = 1 / sum_r uu[r]*M[r,c] ---
        float acc[8] = {0.f,0.f,0.f,0.f,0.f,0.f,0.f,0.f};
#pragma unroll
        for (int k = 0; k < KR; ++k) {
            float w = uu[RL + k * 8 + tr];           // wave-uniform broadcast
#pragma unroll
            for (int j = 0; j < 4; ++j) {
                uint m = mreg[k][j];
                acc[2*j]   += w * h_lo(m);
                acc[2*j+1] += w * h_hi(m);
            }
        }
#pragma unroll
        for (int i = 0; i < 16; ++i) {               // this thread's share of LDS rows
            int r = tr * 16 + i;
            float w = uu[r];                          // wave-uniform broadcast
            const uint* row = mlds + (size_t)r * 256 + tc * 4;
#pragma unroll
            for (int j = 0; j < 4; ++j) {
                uint m = row[j];
                acc[2*j]   += w * h_lo(m);
                acc[2*j+1] += w * h_hi(m);
            }
        }
#pragma unroll
        for (int j = 0; j < 8; ++j) red[(c0 + j) * 9 + tr] = acc[j];
        __syncthreads();
        if (t < 256) {
            int ca = 2 * t, cb = 2 * t + 1;
            float s0 = 0.f, s1 = 0.f;
#pragma unroll
            for (int w = 0; w < 8; ++w) { s0 += red[ca * 9 + w]; s1 += red[cb * 9 + w]; }
            float va = (ca < n) ? 1.f / s0 : 0.f;
            float vb = (cb < n) ? 1.f / s1 : 0.f;
            vf[ca] = va; vf[cb] = vb;
            vpk[t] = h_pk(va, vb);
        }
        __syncthreads();

        // --- row step: uu[r] = 1 / sum_c M[r,c]*vf[c] ---
        uint vp[4];
#pragma unroll
        for (int j = 0; j < 4; ++j) vp[j] = vpk[tc * 4 + j];
#pragma unroll
        for (int k = 0; k < KR; ++k) {
            float p = 0.f;
#pragma unroll
            for (int j = 0; j < 4; ++j) p = dot2(mreg[k][j], vp[j], p);
#pragma unroll
            for (int o = 32; o; o >>= 1) p += __shfl_xor(p, o, 64);
            int r = RL + k * 8 + tr;                 // wave holds all 512 cols of this row
            if (tc == 0) uu[r] = (r < n) ? 1.f / p : 0.f;
        }
        {   // LDS rows: 4 threads per row, rotated start to kill bank conflicts
            int r = t >> 2, q = t & 3;
            const uint* row = mlds + (size_t)r * 256 + q * 64;
            const uint* vq  = vpk + q * 64;
            int rot = t & 63;
            float p0 = 0.f, p1 = 0.f;
#pragma unroll
            for (int j = 0; j < 64; j += 2) {
                int j0 = (j + rot) & 63;
                int j1 = (j + 1 + rot) & 63;
                p0 = dot2(row[j0], vq[j0], p0);
                p1 = dot2(row[j1], vq[j1], p1);
            }
            red[r * 9 + q] = p0 + p1;
        }
        __syncthreads();
        if (t < 128) {                               // rows < 128 are always < n
            float s = red[t*9+0] + red[t*9+1] + red[t*9+2] + red[t*9+3];
            uu[t] = 1.f / s;
        }
        __syncthreads();
    }

    // ---------------- epilogue: out = M * u_r * v_c (zeros propagate the mask) ----------------
    float v8[8];
#pragma unroll
    for (int j = 0; j < 8; ++j) v8[j] = vf[c0 + j];
#pragma unroll
    for (int k = 0; k < KR; ++k) {
        int r = RL + k * 8 + tr;
        float ur = uu[r];
        float4 o0, o1;
        o0.x = h_lo(mreg[k][0]) * ur * v8[0];  o0.y = h_hi(mreg[k][0]) * ur * v8[1];
        o0.z = h_lo(mreg[k][1]) * ur * v8[2];  o0.w = h_hi(mreg[k][1]) * ur * v8[3];
        o1.x = h_lo(mreg[k][2]) * ur * v8[4];  o1.y = h_hi(mreg[k][2]) * ur * v8[5];
        o1.z = h_lo(mreg[k][3]) * ur * v8[6];  o1.w = h_hi(mreg[k][3]) * ur * v8[7];
        float4* po = (float4*)(out + base + (size_t)r * N + c0);
        po[0] = o0; po[1] = o1;
    }
#pragma unroll
    for (int k = 0; k < 16; ++k) {
        int r = k * 8 + tr;
        float ur = uu[r];
        const uint* row = mlds + (size_t)r * 256 + tc * 4;
        uint m0 = row[0], m1 = row[1], m2 = row[2], m3 = row[3];
        float4 o0, o1;
        o0.x = h_lo(m0) * ur * v8[0];  o0.y = h_hi(m0) * ur * v8[1];
        o0.z = h_lo(m1) * ur * v8[2];  o0.w = h_hi(m1) * ur * v8[3];
        o1.x = h_lo(m2) * ur * v8[4];  o1.y = h_hi(m2) * ur * v8[5];
        o1.z = h_lo(m3) * ur * v8[6];  o1.w = h_hi(m3) * ur * v8[7];
        float4* po = (float4*)(out + base + (size_t)r * N + c0);
        po[0] = o0; po[1] = o1;
    }
}

extern "C" void kernel_launch(void* const* d_in, const int* in_sizes, int n_in,
                              void* d_out, int out_size, void* d_ws, size_t ws_size,
                              hipStream_t stream) {
    const float* A     = (const float*)d_in[0];
    const int*   nrows = (const int*)d_in[1];
    float*       out   = (float*)d_out;
    const int    B     = in_sizes[1];   // 128

    // allow >64 KB dynamic LDS (154624 B); idempotent, not a stream op -> capture-safe
    hipFuncSetAttribute(reinterpret_cast<const void*>(k_sink),
                        hipFuncAttributeMaxDynamicSharedMemorySize, LDS_BYTES);

    k_sink<<<B, 512, LDS_BYTES, stream>>>(A, nrows, out);
}

// Round 3
// 324.225 us; speedup vs baseline: 3.3062x; 3.3062x over previous
//
#include <hip/hip_runtime.h>

#define N     512
#define NSP   4          // column stripes per sample
#define SC    128        // columns per stripe
#define MROW  65         // LDS matrix row stride in uints (pad: 65 % 32 == 1)
#define EPS   1e-4f

// LDS layout (uints): M2[512*65] | uu[512]f | red[128*33]f | vf[128]f | vpk[64]
#define LDS_U   (512 * MROW + 512 + 128 * 33 + 128 + 64)
#define LDS_BYTES (LDS_U * 4)

// ---- f16 helpers ----
union U32H { unsigned int u; _Float16 h[2]; };
__device__ inline float h_lo(unsigned int x){ U32H t; t.u = x; return (float)t.h[0]; }
__device__ inline float h_hi(unsigned int x){ U32H t; t.u = x; return (float)t.h[1]; }
__device__ inline unsigned int h_pk(float a, float b){ U32H t; t.h[0]=(_Float16)a; t.h[1]=(_Float16)b; return t.u; }

typedef _Float16 half2v __attribute__((ext_vector_type(2)));
#if __has_builtin(__builtin_amdgcn_fdot2)
__device__ inline float dot2(unsigned int m, unsigned int v, float c){
    return __builtin_amdgcn_fdot2(__builtin_bit_cast(half2v, m), __builtin_bit_cast(half2v, v), c, false);
}
#else
__device__ inline float dot2(unsigned int m, unsigned int v, float c){
    return c + h_lo(m)*h_lo(v) + h_hi(m)*h_hi(v);
}
#endif

// Shared tail of both pass kernels: reduce column sums -> v, then row partials.
__device__ inline void pass_tail(unsigned int* M2, float* red, float* vf, unsigned int* vpk,
                                 const float acc[8], int t, int part, int j, int c0, int n,
                                 int b, int sp, float* __restrict__ rp_out,
                                 float* __restrict__ vf_out) {
#pragma unroll
    for (int k = 0; k < 8; ++k) red[(8*j + k)*33 + part] = acc[k];
    __syncthreads();
    if (t < 128) {
        float s = 0.f;
#pragma unroll
        for (int p = 0; p < 32; ++p) s += red[t*33 + p];
        float v = (c0 + t < n) ? 1.f / s : 0.f;
        vf[t] = v;
        if (vf_out) vf_out[b*N + c0 + t] = v;
    }
    __syncthreads();
    if (t < 64) vpk[t] = h_pk(vf[2*t], vf[2*t+1]);
    __syncthreads();
    // row partial: thread t owns row t; addr t*65+q == (t+q) mod 32 -> conflict-free
    float p = 0.f;
    const unsigned int* row = M2 + t * MROW;
#pragma unroll
    for (int q = 0; q < 64; ++q) p = dot2(row[q], vpk[q], p);
    rp_out[((size_t)b*NSP + sp)*N + t] = p;
}

// ---- pass 0: fp32 read + convert + col-normalize (u=1 via pre-masked zeros) + row partials ----
__global__ __launch_bounds__(512)
void k_pass0(const float* __restrict__ A, const int* __restrict__ nrows,
             unsigned int* __restrict__ Abf, float* __restrict__ rp_out) {
    extern __shared__ unsigned int lds[];
    unsigned int* M2 = lds;
    float* uu = (float*)(lds + 512*MROW);
    float* red = uu + 512;
    float* vf  = red + 128*33;
    unsigned int* vpk = (unsigned int*)(vf + 128);

    const int b = blockIdx.y, sp = blockIdx.x, c0 = sp * SC;
    const int n = nrows[b];
    const int t = threadIdx.x;
    const int w = t >> 6, l = t & 63;
    const int j = l & 15, rg = l >> 4;
    const size_t baseA = (size_t)b * N * N;
    const size_t baseH = (size_t)b * N * (N/2);
    const int cb = c0 + 8*j;

    bool cok[8];
#pragma unroll
    for (int k = 0; k < 8; ++k) cok[k] = (cb + k) < n;

    float acc[8] = {0,0,0,0,0,0,0,0};
    for (int it = 0; it < 16; ++it) {
        int r = it*32 + w*4 + rg;
        const float4* p = (const float4*)(A + baseA + (size_t)r*N + cb);
        float4 a0 = p[0], a1 = p[1];
        bool rok = r < n;
        float e[8];
        e[0] = (rok && cok[0]) ? a0.x + EPS : 0.f;
        e[1] = (rok && cok[1]) ? a0.y + EPS : 0.f;
        e[2] = (rok && cok[2]) ? a0.z + EPS : 0.f;
        e[3] = (rok && cok[3]) ? a0.w + EPS : 0.f;
        e[4] = (rok && cok[4]) ? a1.x + EPS : 0.f;
        e[5] = (rok && cok[5]) ? a1.y + EPS : 0.f;
        e[6] = (rok && cok[6]) ? a1.z + EPS : 0.f;
        e[7] = (rok && cok[7]) ? a1.w + EPS : 0.f;
#pragma unroll
        for (int k = 0; k < 8; ++k) acc[k] += e[k];    // colsum0, u == mask already in e
        uint4 q;
        q.x = h_pk(e[0], e[1]); q.y = h_pk(e[2], e[3]);
        q.z = h_pk(e[4], e[5]); q.w = h_pk(e[6], e[7]);
        *(uint4*)(Abf + baseH + (size_t)r*(N/2) + c0/2 + 4*j) = q;
        unsigned int* dst = M2 + r*MROW + 4*j;
        dst[0] = q.x; dst[1] = q.y; dst[2] = q.z; dst[3] = q.w;
    }
    (void)uu;
    pass_tail(M2, red, vf, vpk, acc, t, w*4 + rg, j, c0, n, b, sp, rp_out, nullptr);
}

// ---- passes 1..4: finalize u from row partials, col-normalize, next row partials ----
__global__ __launch_bounds__(512)
void k_passN(const unsigned int* __restrict__ Abf, const int* __restrict__ nrows,
             const float* __restrict__ rp_in, float* __restrict__ rp_out,
             float* __restrict__ vf_out) {
    extern __shared__ unsigned int lds[];
    unsigned int* M2 = lds;
    float* uu = (float*)(lds + 512*MROW);
    float* red = uu + 512;
    float* vf  = red + 128*33;
    unsigned int* vpk = (unsigned int*)(vf + 128);

    const int b = blockIdx.y, sp = blockIdx.x, c0 = sp * SC;
    const int n = nrows[b];
    const int t = threadIdx.x;
    const int w = t >> 6, l = t & 63;
    const int j = l & 15, rg = l >> 4;
    const size_t baseH = (size_t)b * N * (N/2);

    {   // u[r] = 1 / sum of 4 stripe partials (masked)
        float s = rp_in[((size_t)b*NSP + 0)*N + t]
                + rp_in[((size_t)b*NSP + 1)*N + t]
                + rp_in[((size_t)b*NSP + 2)*N + t]
                + rp_in[((size_t)b*NSP + 3)*N + t];
        uu[t] = (t < n) ? 1.f / s : 0.f;
    }
    __syncthreads();

    float acc[8] = {0,0,0,0,0,0,0,0};
    for (int it = 0; it < 16; ++it) {
        int r = it*32 + w*4 + rg;
        uint4 q = *(const uint4*)(Abf + baseH + (size_t)r*(N/2) + c0/2 + 4*j);
        float ur = uu[r];
        acc[0] += ur * h_lo(q.x); acc[1] += ur * h_hi(q.x);
        acc[2] += ur * h_lo(q.y); acc[3] += ur * h_hi(q.y);
        acc[4] += ur * h_lo(q.z); acc[5] += ur * h_hi(q.z);
        acc[6] += ur * h_lo(q.w); acc[7] += ur * h_hi(q.w);
        unsigned int* dst = M2 + r*MROW + 4*j;
        dst[0] = q.x; dst[1] = q.y; dst[2] = q.z; dst[3] = q.w;
    }
    __syncthreads();   // M2 fully written before pass_tail's row phase
    pass_tail(M2, red, vf, vpk, acc, t, w*4 + rg, j, c0, n, b, sp, rp_out, vf_out);
}

// ---- epilogue: out = (A+eps)*u9[r]*v8[c], masks via ur=0 / v=0 ----
__global__ __launch_bounds__(512)
void k_epi(const float* __restrict__ A, const int* __restrict__ nrows,
           const float* __restrict__ rp9, const float* __restrict__ vf8,
           float* __restrict__ out) {
    const int b = blockIdx.y;
    const int n = nrows[b];
    const int t = threadIdx.x;
    const int r = blockIdx.x*4 + (t >> 7);
    const int c = (t & 127) * 4;
    float s = rp9[((size_t)b*NSP + 0)*N + r]
            + rp9[((size_t)b*NSP + 1)*N + r]
            + rp9[((size_t)b*NSP + 2)*N + r]
            + rp9[((size_t)b*NSP + 3)*N + r];
    float ur = (r < n) ? 1.f / s : 0.f;
    float4 v = *(const float4*)(vf8 + b*N + c);
    const size_t off = (size_t)b*N*N + (size_t)r*N + c;
    float4 a = *(const float4*)(A + off);
    float4 o;
    o.x = (a.x + EPS) * ur * v.x;
    o.y = (a.y + EPS) * ur * v.y;
    o.z = (a.z + EPS) * ur * v.z;
    o.w = (a.w + EPS) * ur * v.w;
    *(float4*)(out + off) = o;
}

extern "C" void kernel_launch(void* const* d_in, const int* in_sizes, int n_in,
                              void* d_out, int out_size, void* d_ws, size_t ws_size,
                              hipStream_t stream) {
    const float* A     = (const float*)d_in[0];
    const int*   nrows = (const int*)d_in[1];
    float*       out   = (float*)d_out;
    const int    B     = in_sizes[1];   // 128

    float* rpA = (float*)d_ws;
    float* rpB = rpA + (size_t)B * NSP * N;
    float* vf8 = rpB + (size_t)B * NSP * N;
    size_t head = ((size_t)2*B*NSP*N + (size_t)B*N) * sizeof(float);
    size_t abf_bytes = (size_t)B * N * (N/2) * sizeof(unsigned int);
    unsigned int* Abf = (ws_size >= head + abf_bytes)
                      ? (unsigned int*)((char*)d_ws + head)
                      : (unsigned int*)d_out;   // safe: epilogue reads A, not Abf

    hipFuncSetAttribute(reinterpret_cast<const void*>(k_pass0),
                        hipFuncAttributeMaxDynamicSharedMemorySize, LDS_BYTES);
    hipFuncSetAttribute(reinterpret_cast<const void*>(k_passN),
                        hipFuncAttributeMaxDynamicSharedMemorySize, LDS_BYTES);

    dim3 g(NSP, B);
    k_pass0<<<g, 512, LDS_BYTES, stream>>>(A, nrows, Abf, rpA);                // v0, rp1
    k_passN<<<g, 512, LDS_BYTES, stream>>>(Abf, nrows, rpA, rpB, nullptr);     // u1,v2, rp3
    k_passN<<<g, 512, LDS_BYTES, stream>>>(Abf, nrows, rpB, rpA, nullptr);     // u3,v4, rp5
    k_passN<<<g, 512, LDS_BYTES, stream>>>(Abf, nrows, rpA, rpB, nullptr);     // u5,v6, rp7
    k_passN<<<g, 512, LDS_BYTES, stream>>>(Abf, nrows, rpB, rpA, vf8);         // u7,v8, rp9
    k_epi<<<dim3(N/4, B), 512, 0, stream>>>(A, nrows, rpA, vf8, out);          // u9, out
}